// Round 7
// baseline (933.460 us; speedup 1.0000x reference)
//
#include <hip/hip_runtime.h>
#include <math.h>

#define TPB 256

constexpr int Bn = 8, Cn = 3, Hn = 1024, Wn = 512;
constexpr long long HWn  = (long long)Hn * Wn;      // 524288 = 2^19
constexpr long long CHWn = (long long)Cn * HWn;     // 1572864
constexpr float INV_NTOT = 1.0f / (float)(Cn * Hn * Wn);
constexpr float EPS10 = 4.5399929762484854e-05f;    // exp(-10)

#define SWZ(x) ((x) + ((x) >> 3))

// ---------------------------------------------------------------------------
// Forward FFT along W (512) — one block per row, real input -> complex out
// LDS swizzled: bit-reversed scatter becomes 2-way (free) instead of 16-way.
// ---------------------------------------------------------------------------
__global__ __launch_bounds__(TPB) void k_fft_w_fwd(const float* __restrict__ x,
                                                   float2* __restrict__ F) {
    __shared__ float sre[576], sim[576], twc[Wn / 2], tws[Wn / 2];
    int r = blockIdx.x;                     // B*C*H rows
    const float* xr = x + (long long)r * Wn;
    float2* Fr = F + (long long)r * Wn;
    int t = threadIdx.x;

    if (t < Wn / 2) {
        float s, c;
        sincospif(-2.0f * (float)t / (float)Wn, &s, &c);  // e^{-2pi i t/512}
        twc[t] = c; tws[t] = s;
    }
    for (int i = t; i < Wn; i += TPB) {
        int j = __brev((unsigned)i) >> (32 - 9);
        sre[SWZ(j)] = xr[i];
        sim[SWZ(j)] = 0.0f;
    }
    __syncthreads();
    #pragma unroll
    for (int st = 0; st < 9; st++) {
        int half = 1 << st;
        int i = t;                           // exactly 256 butterflies
        int blk = i >> st, j = i & (half - 1);
        int pos = (blk << (st + 1)) + j;
        int tid = j << (8 - st);
        float c = twc[tid], s = tws[tid];
        int p0 = SWZ(pos), p1 = SWZ(pos + half);
        float ure = sre[p0], uim = sim[p0];
        float vre = sre[p1], vim = sim[p1];
        float tre = vre * c - vim * s, tim = vre * s + vim * c;
        sre[p0] = ure + tre;  sim[p0] = uim + tim;
        sre[p1] = ure - tre;  sim[p1] = uim - tim;
        __syncthreads();
    }
    for (int i = t; i < Wn; i += TPB)
        Fr[i] = make_float2(sre[SWZ(i)], sim[SWZ(i)]);
}

// ---------------------------------------------------------------------------
// Inverse FFT along W (512) fused with |z| * 1/Ntot -> real SRabs
// ---------------------------------------------------------------------------
__global__ __launch_bounds__(TPB) void k_ifft_w_abs(const float2* __restrict__ F,
                                                    float* __restrict__ SRabs) {
    __shared__ float sre[576], sim[576], twc[Wn / 2], tws[Wn / 2];
    int r = blockIdx.x;
    const float2* Fr = F + (long long)r * Wn;
    float* outr = SRabs + (long long)r * Wn;
    int t = threadIdx.x;

    if (t < Wn / 2) {
        float s, c;
        sincospif(2.0f * (float)t / (float)Wn, &s, &c);   // conjugate twiddles
        twc[t] = c; tws[t] = s;
    }
    for (int i = t; i < Wn; i += TPB) {
        int j = __brev((unsigned)i) >> (32 - 9);
        float2 z = Fr[i];
        sre[SWZ(j)] = z.x;
        sim[SWZ(j)] = z.y;
    }
    __syncthreads();
    #pragma unroll
    for (int st = 0; st < 9; st++) {
        int half = 1 << st;
        int i = t;
        int blk = i >> st, j = i & (half - 1);
        int pos = (blk << (st + 1)) + j;
        int tid = j << (8 - st);
        float c = twc[tid], s = tws[tid];
        int p0 = SWZ(pos), p1 = SWZ(pos + half);
        float ure = sre[p0], uim = sim[p0];
        float vre = sre[p1], vim = sim[p1];
        float tre = vre * c - vim * s, tim = vre * s + vim * c;
        sre[p0] = ure + tre;  sim[p0] = uim + tim;
        sre[p1] = ure - tre;  sim[p1] = uim - tim;
        __syncthreads();
    }
    for (int i = t; i < Wn; i += TPB) {
        float re = sre[SWZ(i)], im = sim[SWZ(i)];
        outr[i] = sqrtf(re * re + im * im) * INV_NTOT;
    }
}

// ---------------------------------------------------------------------------
// FFT along H (1024), strided by W complexes. 4 w-columns per block.
// float4 global I/O (2 complexes/lane). Swizzled LDS (stride 1151, +h>>3):
// scatter drops from 64-way to 4-way bank conflict.
// INV=0 forward, INV=1 inverse (no scaling here).
// ---------------------------------------------------------------------------
template <int INV>
__global__ __launch_bounds__(TPB) void k_fft_h(float2* __restrict__ F) {
    constexpr int CST = 1151;
    __shared__ float sre[4 * CST], sim[4 * CST], twc[Hn / 2], tws[Hn / 2];
    int bid = blockIdx.x;
    int wt = bid & 127;            // W/4 = 128 tiles
    int bc = bid >> 7;             // b*C + c
    float4* base4 = (float4*)(F + (long long)bc * HWn);
    int t = threadIdx.x;

    for (int i = t; i < Hn / 2; i += TPB) {
        float s, c;
        sincospif((INV ? 2.0f : -2.0f) * (float)i / (float)Hn, &s, &c);
        twc[i] = c; tws[i] = s;
    }
    for (int i = t; i < 2048; i += TPB) {
        int h = i >> 1, l = i & 1;
        float4 v = base4[h * (Wn / 2) + wt * 2 + l];
        int hj = __brev((unsigned)h) >> (32 - 10);
        int a = hj + (hj >> 3);
        int w0 = 2 * l;
        sre[w0 * CST + a] = v.x;        sim[w0 * CST + a] = v.y;
        sre[(w0 + 1) * CST + a] = v.z;  sim[(w0 + 1) * CST + a] = v.w;
    }
    __syncthreads();
    for (int st = 0; st < 10; st++) {
        int half = 1 << st;
        #pragma unroll
        for (int qq = 0; qq < 8; qq++) {           // 2048 butterflies / 256 thr
            int q = qq * TPB + t;
            int w = q >> 9;
            int i = q & 511;
            int blk = i >> st, j = i & (half - 1);
            int pos = (blk << (st + 1)) + j;
            int tid = j << (9 - st);
            float c = twc[tid], s = tws[tid];
            int pr = pos + half;
            int p0 = w * CST + pos + (pos >> 3);
            int p1 = w * CST + pr + (pr >> 3);
            float ure = sre[p0], uim = sim[p0];
            float vre = sre[p1], vim = sim[p1];
            float tre = vre * c - vim * s, tim = vre * s + vim * c;
            sre[p0] = ure + tre;  sim[p0] = uim + tim;
            sre[p1] = ure - tre;  sim[p1] = uim - tim;
        }
        __syncthreads();
    }
    for (int i = t; i < 2048; i += TPB) {
        int h = i >> 1, l = i & 1;
        int a = h + (h >> 3);
        int w0 = 2 * l;
        float4 v = make_float4(sre[w0 * CST + a], sim[w0 * CST + a],
                               sre[(w0 + 1) * CST + a], sim[(w0 + 1) * CST + a]);
        base4[h * (Wn / 2) + wt * 2 + l] = v;
    }
}

// ---------------------------------------------------------------------------
// 3-point DFT along C (stride HW), forward, writes ONLY log-amplitude.
// F is left unmodified (X recomputed later in k_compose_cinv).
// ---------------------------------------------------------------------------
__global__ __launch_bounds__(TPB) void k_dft_c_la(const float2* __restrict__ F,
                                                  float* __restrict__ LA) {
    long long idx = (long long)blockIdx.x * TPB + threadIdx.x;   // over B*HW
    if (idx >= (long long)Bn * HWn) return;
    long long b = idx >> 19;
    long long p = idx & (HWn - 1);
    const float2* z = F + b * CHWn + p;
    float2 z0 = z[0], z1 = z[HWn], z2 = z[2 * HWn];
    const float s3 = 0.86602540378443864676f;
    float sx = z1.x + z2.x, sy = z1.y + z2.y;
    float dx = z1.x - z2.x, dy = z1.y - z2.y;
    float2 X0 = make_float2(z0.x + sx, z0.y + sy);
    float2 X1 = make_float2(z0.x - 0.5f * sx + s3 * dy, z0.y - 0.5f * sy - s3 * dx);
    float2 X2 = make_float2(z0.x - 0.5f * sx - s3 * dy, z0.y - 0.5f * sy + s3 * dx);
    float* la = LA + b * CHWn + p;
    la[0]        = logf(sqrtf(X0.x * X0.x + X0.y * X0.y) + EPS10);
    la[HWn]      = logf(sqrtf(X1.x * X1.x + X1.y * X1.y) + EPS10);
    la[2 * HWn]  = logf(sqrtf(X2.x * X2.x + X2.y * X2.y) + EPS10);
}

// ---------------------------------------------------------------------------
// 3x3 channel-summed box conv (zero pad): AF[b,h,w] = 1/9 * sum_c sum_3x3 LA
// ---------------------------------------------------------------------------
__global__ __launch_bounds__(TPB) void k_avgconv(const float* __restrict__ LA,
                                                 float* __restrict__ AF) {
    __shared__ float tile[3][10][34];
    int w0 = blockIdx.x << 5;
    int h0 = blockIdx.y << 3;
    int b = blockIdx.z;
    int t = threadIdx.x;
    for (int i = t; i < 3 * 10 * 34; i += TPB) {
        int c = i / 340, rem = i - c * 340;
        int hh = rem / 34, ww = rem - hh * 34;
        int h = h0 + hh - 1, w = w0 + ww - 1;
        float v = 0.0f;
        if ((unsigned)h < (unsigned)Hn && (unsigned)w < (unsigned)Wn)
            v = LA[((long long)b * 3 + c) * HWn + (long long)h * Wn + w];
        tile[c][hh][ww] = v;
    }
    __syncthreads();
    int ww = t & 31, hh = t >> 5;
    float acc = 0.0f;
    #pragma unroll
    for (int c = 0; c < 3; c++)
        #pragma unroll
        for (int dh = 0; dh < 3; dh++)
            #pragma unroll
            for (int dw = 0; dw < 3; dw++)
                acc += tile[c][hh + dh][ww + dw];
    AF[(long long)b * HWn + (long long)(h0 + hh) * Wn + (w0 + ww)] = acc * (1.0f / 9.0f);
}

// ---------------------------------------------------------------------------
// Fused: recompute forward C-DFT (X), apply G = exp(LA-AF)*X/|X|, then
// inverse 3-point C-DFT, write back into F. Saves a full 100MB+100MB pass.
// ---------------------------------------------------------------------------
__global__ __launch_bounds__(TPB) void k_compose_cinv(float2* __restrict__ F,
                                                      const float* __restrict__ LA,
                                                      const float* __restrict__ AF) {
    long long idx = (long long)blockIdx.x * TPB + threadIdx.x;   // over B*HW
    if (idx >= (long long)Bn * HWn) return;
    long long b = idx >> 19;
    long long p = idx & (HWn - 1);
    float2* z = F + b * CHWn + p;
    const float* la = LA + b * CHWn + p;
    float af = AF[idx];
    const float s3 = 0.86602540378443864676f;

    float2 z0 = z[0], z1 = z[HWn], z2 = z[2 * HWn];
    float sx = z1.x + z2.x, sy = z1.y + z2.y;
    float dx = z1.x - z2.x, dy = z1.y - z2.y;
    float2 X[3];
    X[0] = make_float2(z0.x + sx, z0.y + sy);
    X[1] = make_float2(z0.x - 0.5f * sx + s3 * dy, z0.y - 0.5f * sy - s3 * dx);
    X[2] = make_float2(z0.x - 0.5f * sx - s3 * dy, z0.y - 0.5f * sy + s3 * dx);

    float2 g[3];
    #pragma unroll
    for (int c = 0; c < 3; c++) {
        float m = expf(la[c * HWn] - af);
        float r = sqrtf(X[c].x * X[c].x + X[c].y * X[c].y);
        if (r > 0.0f) {
            float sc = m / r;
            g[c] = make_float2(X[c].x * sc, X[c].y * sc);
        } else {
            g[c] = make_float2(m, 0.0f);
        }
    }
    // inverse 3-point DFT
    float gsx = g[1].x + g[2].x, gsy = g[1].y + g[2].y;
    float gdx = g[1].x - g[2].x, gdy = g[1].y - g[2].y;
    z[0]       = make_float2(g[0].x + gsx, g[0].y + gsy);
    z[HWn]     = make_float2(g[0].x - 0.5f * gsx - s3 * gdy, g[0].y - 0.5f * gsy + s3 * gdx);
    z[2 * HWn] = make_float2(g[0].x - 0.5f * gsx + s3 * gdy, g[0].y - 0.5f * gsy - s3 * gdx);
}

// ---------------------------------------------------------------------------
// 3x3 channel-summed Gaussian conv (zero pad) -> SRg (B,H,W), fused with
// per-batch sum accumulation (atomicAdd of raw block sums into meanacc[b]).
// ---------------------------------------------------------------------------
__global__ __launch_bounds__(TPB) void k_gauconv(const float* __restrict__ SRa,
                                                 float* __restrict__ SRg,
                                                 float* __restrict__ meanacc) {
    __shared__ float tile[3][10][34];
    int w0 = blockIdx.x << 5;
    int h0 = blockIdx.y << 3;
    int b = blockIdx.z;
    int t = threadIdx.x;
    for (int i = t; i < 3 * 10 * 34; i += TPB) {
        int c = i / 340, rem = i - c * 340;
        int hh = rem / 34, ww = rem - hh * 34;
        int h = h0 + hh - 1, w = w0 + ww - 1;
        float v = 0.0f;
        if ((unsigned)h < (unsigned)Hn && (unsigned)w < (unsigned)Wn)
            v = SRa[((long long)b * 3 + c) * HWn + (long long)h * Wn + w];
        tile[c][hh][ww] = v;
    }
    __syncthreads();
    const float g16 = 1.0f / 16.0f, g8 = 1.0f / 8.0f, g4 = 1.0f / 4.0f;
    const float wgt[3][3] = {{g16, g8, g16}, {g8, g4, g8}, {g16, g8, g16}};
    int ww = t & 31, hh = t >> 5;
    float acc = 0.0f;
    #pragma unroll
    for (int c = 0; c < 3; c++)
        #pragma unroll
        for (int dh = 0; dh < 3; dh++)
            #pragma unroll
            for (int dw = 0; dw < 3; dw++)
                acc += wgt[dh][dw] * tile[c][hh + dh][ww + dw];
    SRg[(long long)b * HWn + (long long)(h0 + hh) * Wn + (w0 + ww)] = acc;

    // block-level partial sum for the mean
    float s = acc;
    #pragma unroll
    for (int o = 32; o > 0; o >>= 1)
        s += __shfl_down(s, o);
    __shared__ float ls[4];
    if ((t & 63) == 0) ls[t >> 6] = s;
    __syncthreads();
    if (t == 0)
        atomicAdd(&meanacc[b], ls[0] + ls[1] + ls[2] + ls[3]);
}

// ---------------------------------------------------------------------------
// Final: out[b,h,o] = b_out[o] + sum_{w,k} thr(SRg[b,(h+k-1)%H,w]) * w_out[o,w,k]
// 128h x 64o tile per block, 8x4 per thread. A kept transposed in LDS
// (As[w][row], stride 132 => 16B-aligned b128 reads, conflict-free).
// ---------------------------------------------------------------------------
__global__ __launch_bounds__(TPB) void k_outgemm(const float* __restrict__ SRg,
                                                 const float* __restrict__ meanacc,
                                                 const float* __restrict__ w_out,
                                                 const float* __restrict__ b_out,
                                                 float* __restrict__ out) {
    __shared__ __align__(16) float As[32][132];   // [w][row 0..129]
    __shared__ __align__(16) float Bs[3][32][64];
    int o0 = blockIdx.x << 6;
    int h0 = blockIdx.y << 7;
    int b = blockIdx.z;
    int t = threadIdx.x;
    int to = t & 15, th = t >> 4;
    float meanb = meanacc[b] * (1.0f / (float)HWn);
    const float* srb = SRg + (long long)b * HWn;

    float acc[8][4];
    #pragma unroll
    for (int i = 0; i < 8; i++)
        #pragma unroll
        for (int j = 0; j < 4; j++) acc[i][j] = 0.0f;

    for (int w0 = 0; w0 < Wn; w0 += 32) {
        // A tile: rows h0-1 .. h0+128 (wrap), 32 w columns; threshold applied
        for (int i = t; i < 130 * 32; i += TPB) {
            int r = i >> 5, wc = i & 31;
            int h = (h0 - 1 + r) & (Hn - 1);
            float v = srb[(long long)h * Wn + w0 + wc];
            As[wc][r] = (v > meanb) ? v : 0.0f;
        }
        // B tile: w_out[o][w][k] -> Bs[k][w][oo]
        {
            int oo = t & 63, g = t >> 6;
            const float4* wpv = (const float4*)(w_out +
                (long long)(o0 + oo) * 1536 + (long long)w0 * 3 + g * 24);
            #pragma unroll
            for (int j2 = 0; j2 < 6; j2++) {
                float4 v4 = wpv[j2];
                int mm = j2 * 4;
                Bs[(mm) % 3][g * 8 + (mm) / 3][oo]         = v4.x;
                Bs[(mm + 1) % 3][g * 8 + (mm + 1) / 3][oo] = v4.y;
                Bs[(mm + 2) % 3][g * 8 + (mm + 2) / 3][oo] = v4.z;
                Bs[(mm + 3) % 3][g * 8 + (mm + 3) / 3][oo] = v4.w;
            }
        }
        __syncthreads();
        for (int w = 0; w < 32; w++) {
            float4 a03 = *(const float4*)&As[w][th << 3];
            float4 a47 = *(const float4*)&As[w][(th << 3) + 4];
            float2 a89 = *(const float2*)&As[w][(th << 3) + 8];
            float a[10] = {a03.x, a03.y, a03.z, a03.w,
                           a47.x, a47.y, a47.z, a47.w, a89.x, a89.y};
            #pragma unroll
            for (int k = 0; k < 3; k++) {
                float4 bv = *(const float4*)&Bs[k][w][to << 2];
                #pragma unroll
                for (int i2 = 0; i2 < 8; i2++) {
                    acc[i2][0] += a[i2 + k] * bv.x;
                    acc[i2][1] += a[i2 + k] * bv.y;
                    acc[i2][2] += a[i2 + k] * bv.z;
                    acc[i2][3] += a[i2 + k] * bv.w;
                }
            }
        }
        __syncthreads();
    }

    float4 bias = *(const float4*)&b_out[o0 + (to << 2)];
    #pragma unroll
    for (int i2 = 0; i2 < 8; i2++) {
        int h = h0 + (th << 3) + i2;
        float4 v = make_float4(acc[i2][0] + bias.x, acc[i2][1] + bias.y,
                               acc[i2][2] + bias.z, acc[i2][3] + bias.w);
        *(float4*)&out[((long long)b * Hn + h) * 512 + o0 + (to << 2)] = v;
    }
}

// ---------------------------------------------------------------------------
extern "C" void kernel_launch(void* const* d_in, const int* in_sizes, int n_in,
                              void* d_out, int out_size, void* d_ws, size_t ws_size,
                              hipStream_t stream) {
    (void)in_sizes; (void)n_in; (void)out_size;
    const float* x     = (const float*)d_in[0];
    const float* w_out = (const float*)d_in[1];
    const float* b_out = (const float*)d_in[2];
    float* out = (float*)d_out;

    const size_t CBUF_BYTES = (size_t)Bn * CHWn * sizeof(float2);  // 100663296
    const size_t LA_BYTES   = (size_t)Bn * CHWn * sizeof(float);   //  50331648
    const size_t AF_BYTES   = (size_t)Bn * HWn * sizeof(float);    //  16777216
    const size_t NEED = CBUF_BYTES + LA_BYTES + AF_BYTES + 64;
    if (ws_size < NEED) return;

    char* ws = (char*)d_ws;
    float2* CBUF = (float2*)ws;
    float*  LA   = (float*)(ws + CBUF_BYTES);
    float*  AF   = (float*)(ws + CBUF_BYTES + LA_BYTES);
    float*  MEAN = (float*)(ws + CBUF_BYTES + LA_BYTES + AF_BYTES);

    hipMemsetAsync(MEAN, 0, 8 * sizeof(float), stream);

    // forward FFT: W, H; C-DFT computes log-amp only (F left pre-C-DFT)
    k_fft_w_fwd<<<Bn * Cn * Hn, TPB, 0, stream>>>(x, CBUF);
    k_fft_h<0><<<Bn * Cn * (Wn / 4), TPB, 0, stream>>>(CBUF);
    k_dft_c_la<<<(int)((Bn * HWn) / TPB), TPB, 0, stream>>>(CBUF, LA);

    // spectral residual
    k_avgconv<<<dim3(Wn / 32, Hn / 8, Bn), TPB, 0, stream>>>(LA, AF);
    k_compose_cinv<<<(int)((Bn * HWn) / TPB), TPB, 0, stream>>>(CBUF, LA, AF);

    // inverse FFT: H, W (W fused with abs + 1/N)
    k_fft_h<1><<<Bn * Cn * (Wn / 4), TPB, 0, stream>>>(CBUF);
    k_ifft_w_abs<<<Bn * Cn * Hn, TPB, 0, stream>>>(CBUF, LA);   // SRabs -> LA

    // gaussian conv (+mean) + threshold(in GEMM) + output conv
    k_gauconv<<<dim3(Wn / 32, Hn / 8, Bn), TPB, 0, stream>>>(LA, AF, MEAN);  // SRg -> AF
    k_outgemm<<<dim3(8, 8, Bn), TPB, 0, stream>>>(AF, MEAN, w_out, b_out, out);
}

// Round 8
// 747.285 us; speedup vs baseline: 1.2491x; 1.2491x over previous
//
#include <hip/hip_runtime.h>
#include <math.h>

#define TPB 256

constexpr int Bn = 8, Cn = 3, Hn = 1024, Wn = 512;
constexpr long long HWn  = (long long)Hn * Wn;      // 524288 = 2^19
constexpr long long CHWn = (long long)Cn * HWn;     // 1572864
constexpr float INV_NTOT = 1.0f / (float)(Cn * Hn * Wn);
constexpr float EPS10 = 4.5399929762484854e-05f;    // exp(-10)

#define SWZ(x) ((x) + ((x) >> 3))

// ---------------------------------------------------------------------------
// Forward FFT along W (512) — one block per row, real input -> complex out
// ---------------------------------------------------------------------------
__global__ __launch_bounds__(TPB) void k_fft_w_fwd(const float* __restrict__ x,
                                                   float2* __restrict__ F) {
    __shared__ float sre[576], sim[576], twc[Wn / 2], tws[Wn / 2];
    int r = blockIdx.x;                     // B*C*H rows
    const float* xr = x + (long long)r * Wn;
    float2* Fr = F + (long long)r * Wn;
    int t = threadIdx.x;

    if (t < Wn / 2) {
        float s, c;
        sincospif(-2.0f * (float)t / (float)Wn, &s, &c);  // e^{-2pi i t/512}
        twc[t] = c; tws[t] = s;
    }
    for (int i = t; i < Wn; i += TPB) {
        int j = __brev((unsigned)i) >> (32 - 9);
        sre[SWZ(j)] = xr[i];
        sim[SWZ(j)] = 0.0f;
    }
    __syncthreads();
    #pragma unroll
    for (int st = 0; st < 9; st++) {
        int half = 1 << st;
        int i = t;                           // exactly 256 butterflies
        int blk = i >> st, j = i & (half - 1);
        int pos = (blk << (st + 1)) + j;
        int tid = j << (8 - st);
        float c = twc[tid], s = tws[tid];
        int p0 = SWZ(pos), p1 = SWZ(pos + half);
        float ure = sre[p0], uim = sim[p0];
        float vre = sre[p1], vim = sim[p1];
        float tre = vre * c - vim * s, tim = vre * s + vim * c;
        sre[p0] = ure + tre;  sim[p0] = uim + tim;
        sre[p1] = ure - tre;  sim[p1] = uim - tim;
        __syncthreads();
    }
    for (int i = t; i < Wn; i += TPB)
        Fr[i] = make_float2(sre[SWZ(i)], sim[SWZ(i)]);
}

// ---------------------------------------------------------------------------
// Inverse FFT along W (512) fused with |z| * 1/Ntot -> real SRabs
// ---------------------------------------------------------------------------
__global__ __launch_bounds__(TPB) void k_ifft_w_abs(const float2* __restrict__ F,
                                                    float* __restrict__ SRabs) {
    __shared__ float sre[576], sim[576], twc[Wn / 2], tws[Wn / 2];
    int r = blockIdx.x;
    const float2* Fr = F + (long long)r * Wn;
    float* outr = SRabs + (long long)r * Wn;
    int t = threadIdx.x;

    if (t < Wn / 2) {
        float s, c;
        sincospif(2.0f * (float)t / (float)Wn, &s, &c);   // conjugate twiddles
        twc[t] = c; tws[t] = s;
    }
    for (int i = t; i < Wn; i += TPB) {
        int j = __brev((unsigned)i) >> (32 - 9);
        float2 z = Fr[i];
        sre[SWZ(j)] = z.x;
        sim[SWZ(j)] = z.y;
    }
    __syncthreads();
    #pragma unroll
    for (int st = 0; st < 9; st++) {
        int half = 1 << st;
        int i = t;
        int blk = i >> st, j = i & (half - 1);
        int pos = (blk << (st + 1)) + j;
        int tid = j << (8 - st);
        float c = twc[tid], s = tws[tid];
        int p0 = SWZ(pos), p1 = SWZ(pos + half);
        float ure = sre[p0], uim = sim[p0];
        float vre = sre[p1], vim = sim[p1];
        float tre = vre * c - vim * s, tim = vre * s + vim * c;
        sre[p0] = ure + tre;  sim[p0] = uim + tim;
        sre[p1] = ure - tre;  sim[p1] = uim - tim;
        __syncthreads();
    }
    for (int i = t; i < Wn; i += TPB) {
        float re = sre[SWZ(i)], im = sim[SWZ(i)];
        outr[i] = sqrtf(re * re + im * im) * INV_NTOT;
    }
}

// ---------------------------------------------------------------------------
// FFT along H (1024), strided by W complexes. 4 w-columns per block.
// ---------------------------------------------------------------------------
template <int INV>
__global__ __launch_bounds__(TPB) void k_fft_h(float2* __restrict__ F) {
    constexpr int CST = 1151;
    __shared__ float sre[4 * CST], sim[4 * CST], twc[Hn / 2], tws[Hn / 2];
    int bid = blockIdx.x;
    int wt = bid & 127;            // W/4 = 128 tiles
    int bc = bid >> 7;             // b*C + c
    float4* base4 = (float4*)(F + (long long)bc * HWn);
    int t = threadIdx.x;

    for (int i = t; i < Hn / 2; i += TPB) {
        float s, c;
        sincospif((INV ? 2.0f : -2.0f) * (float)i / (float)Hn, &s, &c);
        twc[i] = c; tws[i] = s;
    }
    for (int i = t; i < 2048; i += TPB) {
        int h = i >> 1, l = i & 1;
        float4 v = base4[h * (Wn / 2) + wt * 2 + l];
        int hj = __brev((unsigned)h) >> (32 - 10);
        int a = hj + (hj >> 3);
        int w0 = 2 * l;
        sre[w0 * CST + a] = v.x;        sim[w0 * CST + a] = v.y;
        sre[(w0 + 1) * CST + a] = v.z;  sim[(w0 + 1) * CST + a] = v.w;
    }
    __syncthreads();
    for (int st = 0; st < 10; st++) {
        int half = 1 << st;
        #pragma unroll
        for (int qq = 0; qq < 8; qq++) {           // 2048 butterflies / 256 thr
            int q = qq * TPB + t;
            int w = q >> 9;
            int i = q & 511;
            int blk = i >> st, j = i & (half - 1);
            int pos = (blk << (st + 1)) + j;
            int tid = j << (9 - st);
            float c = twc[tid], s = tws[tid];
            int pr = pos + half;
            int p0 = w * CST + pos + (pos >> 3);
            int p1 = w * CST + pr + (pr >> 3);
            float ure = sre[p0], uim = sim[p0];
            float vre = sre[p1], vim = sim[p1];
            float tre = vre * c - vim * s, tim = vre * s + vim * c;
            sre[p0] = ure + tre;  sim[p0] = uim + tim;
            sre[p1] = ure - tre;  sim[p1] = uim - tim;
        }
        __syncthreads();
    }
    for (int i = t; i < 2048; i += TPB) {
        int h = i >> 1, l = i & 1;
        int a = h + (h >> 3);
        int w0 = 2 * l;
        float4 v = make_float4(sre[w0 * CST + a], sim[w0 * CST + a],
                               sre[(w0 + 1) * CST + a], sim[(w0 + 1) * CST + a]);
        base4[h * (Wn / 2) + wt * 2 + l] = v;
    }
}

// ---------------------------------------------------------------------------
// 3-point DFT along C (stride HW), forward, writes ONLY log-amplitude.
// ---------------------------------------------------------------------------
__global__ __launch_bounds__(TPB) void k_dft_c_la(const float2* __restrict__ F,
                                                  float* __restrict__ LA) {
    long long idx = (long long)blockIdx.x * TPB + threadIdx.x;   // over B*HW
    if (idx >= (long long)Bn * HWn) return;
    long long b = idx >> 19;
    long long p = idx & (HWn - 1);
    const float2* z = F + b * CHWn + p;
    float2 z0 = z[0], z1 = z[HWn], z2 = z[2 * HWn];
    const float s3 = 0.86602540378443864676f;
    float sx = z1.x + z2.x, sy = z1.y + z2.y;
    float dx = z1.x - z2.x, dy = z1.y - z2.y;
    float2 X0 = make_float2(z0.x + sx, z0.y + sy);
    float2 X1 = make_float2(z0.x - 0.5f * sx + s3 * dy, z0.y - 0.5f * sy - s3 * dx);
    float2 X2 = make_float2(z0.x - 0.5f * sx - s3 * dy, z0.y - 0.5f * sy + s3 * dx);
    float* la = LA + b * CHWn + p;
    la[0]        = logf(sqrtf(X0.x * X0.x + X0.y * X0.y) + EPS10);
    la[HWn]      = logf(sqrtf(X1.x * X1.x + X1.y * X1.y) + EPS10);
    la[2 * HWn]  = logf(sqrtf(X2.x * X2.x + X2.y * X2.y) + EPS10);
}

// ---------------------------------------------------------------------------
// 3x3 channel-summed separable conv (zero pad), 128w x 8h tile, float4 I/O.
// GAU=0: box 1/9 (ave_k). GAU=1: gaussian 1/16 outer([1,2,1],[1,2,1]) AND
// per-block partial sum -> part[] (no atomics; k_mean_final reduces).
// ---------------------------------------------------------------------------
template <int GAU>
__global__ __launch_bounds__(TPB) void k_conv3x3(const float* __restrict__ src,
                                                 float* __restrict__ dst,
                                                 float* __restrict__ part) {
    __shared__ float tile[3][10][140];   // rows padded to 140 (16B-aligned)
    int w0 = blockIdx.x << 7;            // 0,128,256,384
    int h0 = blockIdx.y << 3;
    int b  = blockIdx.z;
    int t  = threadIdx.x;

    // halo load: cols w0-4 .. w0+131 (34 float4 per row), rows h0-1..h0+8
    for (int i = t; i < 1020; i += TPB) {          // 3*10*34
        int c = i / 340, rem = i - c * 340;
        int hh = rem / 34, w4 = rem - hh * 34;
        int h  = h0 + hh - 1;
        int gw = w0 - 4 + (w4 << 2);               // only -4 / 512 go OOB
        float4 v = make_float4(0.f, 0.f, 0.f, 0.f);
        if ((unsigned)h < (unsigned)Hn && (unsigned)gw <= 508u)
            v = *(const float4*)(src + ((long long)(b * 3 + c)) * HWn +
                                 (long long)h * Wn + gw);
        *(float4*)&tile[c][hh][w4 << 2] = v;
    }
    __syncthreads();

    const float K = GAU ? 2.0f : 1.0f;
    const float norm = GAU ? (1.0f / 16.0f) : (1.0f / 9.0f);
    int hh = t >> 5;            // 0..7
    int wb = (t & 31) << 2;     // 0..124
    float o0 = 0.f, o1 = 0.f, o2 = 0.f, o3 = 0.f;
    #pragma unroll
    for (int c = 0; c < 3; c++)
        #pragma unroll
        for (int dh = 0; dh < 3; dh++) {
            const float* row = &tile[c][hh + dh][3 + wb];
            float a0 = row[0], a1 = row[1], a2 = row[2],
                  a3 = row[3], a4 = row[4], a5 = row[5];
            float vw = (dh == 1) ? K : 1.0f;
            o0 += vw * (a0 + K * a1 + a2);
            o1 += vw * (a1 + K * a2 + a3);
            o2 += vw * (a2 + K * a3 + a4);
            o3 += vw * (a3 + K * a4 + a5);
        }
    o0 *= norm; o1 *= norm; o2 *= norm; o3 *= norm;
    *(float4*)(dst + (long long)b * HWn + (long long)(h0 + hh) * Wn + w0 + wb)
        = make_float4(o0, o1, o2, o3);

    if (GAU) {                  // per-block partial for the batch mean
        float s = o0 + o1 + o2 + o3;
        #pragma unroll
        for (int o = 32; o > 0; o >>= 1) s += __shfl_down(s, o);
        __shared__ float ls[4];
        if ((t & 63) == 0) ls[t >> 6] = s;
        __syncthreads();
        if (t == 0)
            part[((long long)b << 9) + (blockIdx.y << 2) + blockIdx.x]
                = ls[0] + ls[1] + ls[2] + ls[3];
    }
}

// ---------------------------------------------------------------------------
// Reduce 512 per-block partials per batch -> mean[b]. 8 blocks, no atomics.
// ---------------------------------------------------------------------------
__global__ __launch_bounds__(TPB) void k_mean_final(const float* __restrict__ part,
                                                    float* __restrict__ mean) {
    int b = blockIdx.x;
    int t = threadIdx.x;
    float s = part[(b << 9) + t] + part[(b << 9) + 256 + t];
    #pragma unroll
    for (int o = 32; o > 0; o >>= 1) s += __shfl_down(s, o);
    __shared__ float ls[4];
    if ((t & 63) == 0) ls[t >> 6] = s;
    __syncthreads();
    if (t == 0)
        mean[b] = (ls[0] + ls[1] + ls[2] + ls[3]) * (1.0f / (float)HWn);
}

// ---------------------------------------------------------------------------
// Fused: recompute forward C-DFT (X), apply G = exp(LA-AF)*X/|X|, then
// inverse 3-point C-DFT, write back into F.
// ---------------------------------------------------------------------------
__global__ __launch_bounds__(TPB) void k_compose_cinv(float2* __restrict__ F,
                                                      const float* __restrict__ LA,
                                                      const float* __restrict__ AF) {
    long long idx = (long long)blockIdx.x * TPB + threadIdx.x;   // over B*HW
    if (idx >= (long long)Bn * HWn) return;
    long long b = idx >> 19;
    long long p = idx & (HWn - 1);
    float2* z = F + b * CHWn + p;
    const float* la = LA + b * CHWn + p;
    float af = AF[idx];
    const float s3 = 0.86602540378443864676f;

    float2 z0 = z[0], z1 = z[HWn], z2 = z[2 * HWn];
    float sx = z1.x + z2.x, sy = z1.y + z2.y;
    float dx = z1.x - z2.x, dy = z1.y - z2.y;
    float2 X[3];
    X[0] = make_float2(z0.x + sx, z0.y + sy);
    X[1] = make_float2(z0.x - 0.5f * sx + s3 * dy, z0.y - 0.5f * sy - s3 * dx);
    X[2] = make_float2(z0.x - 0.5f * sx - s3 * dy, z0.y - 0.5f * sy + s3 * dx);

    float2 g[3];
    #pragma unroll
    for (int c = 0; c < 3; c++) {
        float m = expf(la[c * HWn] - af);
        float r = sqrtf(X[c].x * X[c].x + X[c].y * X[c].y);
        if (r > 0.0f) {
            float sc = m / r;
            g[c] = make_float2(X[c].x * sc, X[c].y * sc);
        } else {
            g[c] = make_float2(m, 0.0f);
        }
    }
    // inverse 3-point DFT
    float gsx = g[1].x + g[2].x, gsy = g[1].y + g[2].y;
    float gdx = g[1].x - g[2].x, gdy = g[1].y - g[2].y;
    z[0]       = make_float2(g[0].x + gsx, g[0].y + gsy);
    z[HWn]     = make_float2(g[0].x - 0.5f * gsx - s3 * gdy, g[0].y - 0.5f * gsy + s3 * gdx);
    z[2 * HWn] = make_float2(g[0].x - 0.5f * gsx + s3 * gdy, g[0].y - 0.5f * gsy - s3 * gdx);
}

// ---------------------------------------------------------------------------
// Final: out[b,h,o] = b_out[o] + sum_{w,k} thr(SRg[b,(h+k-1)%H,w]) * w_out[o,w,k]
// ---------------------------------------------------------------------------
__global__ __launch_bounds__(TPB) void k_outgemm(const float* __restrict__ SRg,
                                                 const float* __restrict__ meanv,
                                                 const float* __restrict__ w_out,
                                                 const float* __restrict__ b_out,
                                                 float* __restrict__ out) {
    __shared__ __align__(16) float As[32][132];   // [w][row 0..129]
    __shared__ __align__(16) float Bs[3][32][64];
    int o0 = blockIdx.x << 6;
    int h0 = blockIdx.y << 7;
    int b = blockIdx.z;
    int t = threadIdx.x;
    int to = t & 15, th = t >> 4;
    float meanb = meanv[b];
    const float* srb = SRg + (long long)b * HWn;

    float acc[8][4];
    #pragma unroll
    for (int i = 0; i < 8; i++)
        #pragma unroll
        for (int j = 0; j < 4; j++) acc[i][j] = 0.0f;

    for (int w0 = 0; w0 < Wn; w0 += 32) {
        for (int i = t; i < 130 * 32; i += TPB) {
            int r = i >> 5, wc = i & 31;
            int h = (h0 - 1 + r) & (Hn - 1);
            float v = srb[(long long)h * Wn + w0 + wc];
            As[wc][r] = (v > meanb) ? v : 0.0f;
        }
        {
            int oo = t & 63, g = t >> 6;
            const float4* wpv = (const float4*)(w_out +
                (long long)(o0 + oo) * 1536 + (long long)w0 * 3 + g * 24);
            #pragma unroll
            for (int j2 = 0; j2 < 6; j2++) {
                float4 v4 = wpv[j2];
                int mm = j2 * 4;
                Bs[(mm) % 3][g * 8 + (mm) / 3][oo]         = v4.x;
                Bs[(mm + 1) % 3][g * 8 + (mm + 1) / 3][oo] = v4.y;
                Bs[(mm + 2) % 3][g * 8 + (mm + 2) / 3][oo] = v4.z;
                Bs[(mm + 3) % 3][g * 8 + (mm + 3) / 3][oo] = v4.w;
            }
        }
        __syncthreads();
        for (int w = 0; w < 32; w++) {
            float4 a03 = *(const float4*)&As[w][th << 3];
            float4 a47 = *(const float4*)&As[w][(th << 3) + 4];
            float2 a89 = *(const float2*)&As[w][(th << 3) + 8];
            float a[10] = {a03.x, a03.y, a03.z, a03.w,
                           a47.x, a47.y, a47.z, a47.w, a89.x, a89.y};
            #pragma unroll
            for (int k = 0; k < 3; k++) {
                float4 bv = *(const float4*)&Bs[k][w][to << 2];
                #pragma unroll
                for (int i2 = 0; i2 < 8; i2++) {
                    acc[i2][0] += a[i2 + k] * bv.x;
                    acc[i2][1] += a[i2 + k] * bv.y;
                    acc[i2][2] += a[i2 + k] * bv.z;
                    acc[i2][3] += a[i2 + k] * bv.w;
                }
            }
        }
        __syncthreads();
    }

    float4 bias = *(const float4*)&b_out[o0 + (to << 2)];
    #pragma unroll
    for (int i2 = 0; i2 < 8; i2++) {
        int h = h0 + (th << 3) + i2;
        float4 v = make_float4(acc[i2][0] + bias.x, acc[i2][1] + bias.y,
                               acc[i2][2] + bias.z, acc[i2][3] + bias.w);
        *(float4*)&out[((long long)b * Hn + h) * 512 + o0 + (to << 2)] = v;
    }
}

// ---------------------------------------------------------------------------
extern "C" void kernel_launch(void* const* d_in, const int* in_sizes, int n_in,
                              void* d_out, int out_size, void* d_ws, size_t ws_size,
                              hipStream_t stream) {
    (void)in_sizes; (void)n_in; (void)out_size;
    const float* x     = (const float*)d_in[0];
    const float* w_out = (const float*)d_in[1];
    const float* b_out = (const float*)d_in[2];
    float* out = (float*)d_out;

    const size_t CBUF_BYTES = (size_t)Bn * CHWn * sizeof(float2);  // 100663296
    const size_t LA_BYTES   = (size_t)Bn * CHWn * sizeof(float);   //  50331648
    const size_t AF_BYTES   = (size_t)Bn * HWn * sizeof(float);    //  16777216
    const size_t NEED = CBUF_BYTES + LA_BYTES + AF_BYTES + 64 + 4096 * sizeof(float);
    if (ws_size < NEED) return;

    char* ws = (char*)d_ws;
    float2* CBUF = (float2*)ws;
    float*  LA   = (float*)(ws + CBUF_BYTES);
    float*  AF   = (float*)(ws + CBUF_BYTES + LA_BYTES);
    float*  MEAN = (float*)(ws + CBUF_BYTES + LA_BYTES + AF_BYTES);
    float*  PART = (float*)(ws + CBUF_BYTES + LA_BYTES + AF_BYTES + 64);

    // forward FFT: W, H; C-DFT computes log-amp only (F left pre-C-DFT)
    k_fft_w_fwd<<<Bn * Cn * Hn, TPB, 0, stream>>>(x, CBUF);
    k_fft_h<0><<<Bn * Cn * (Wn / 4), TPB, 0, stream>>>(CBUF);
    k_dft_c_la<<<(int)((Bn * HWn) / TPB), TPB, 0, stream>>>(CBUF, LA);

    // spectral residual
    k_conv3x3<0><<<dim3(4, 128, 8), TPB, 0, stream>>>(LA, AF, nullptr);
    k_compose_cinv<<<(int)((Bn * HWn) / TPB), TPB, 0, stream>>>(CBUF, LA, AF);

    // inverse FFT: H, W (W fused with abs + 1/N)
    k_fft_h<1><<<Bn * Cn * (Wn / 4), TPB, 0, stream>>>(CBUF);
    k_ifft_w_abs<<<Bn * Cn * Hn, TPB, 0, stream>>>(CBUF, LA);   // SRabs -> LA

    // gaussian conv (+block partials) + mean + threshold(in GEMM) + output conv
    k_conv3x3<1><<<dim3(4, 128, 8), TPB, 0, stream>>>(LA, AF, PART);  // SRg -> AF
    k_mean_final<<<8, TPB, 0, stream>>>(PART, MEAN);
    k_outgemm<<<dim3(8, 8, Bn), TPB, 0, stream>>>(AF, MEAN, w_out, b_out, out);
}